// Round 1
// baseline (723.634 us; speedup 1.0000x reference)
//
#include <hip/hip_runtime.h>

// MultipleKmeans: T=16384 frames, E=1024, M=8 models, K=512 clusters.
// Round 1: correct fp32 vector baseline with fp64-accurate argmin.
//
// ws layout (all recomputed every call; ws is re-poisoned between calls):
//   [     0, 32768): double csq[M*K]        centroid squared norms (fp64)
//   [ 32768, 33280): int    hist[16][8]     per-block model histograms
//   [ 33280, 33344): int    offs[9] (+pad)  model offsets into `order`
//   [ 33344, 98880): int    order[T]        frame ids grouped by model

#define T_FRAMES 16384
#define E_DIM    1024
#define M_MODELS 8
#define K_CLUST  512

#define FPB 32   // frames per block (main kernel)
#define KC  64   // centroid tile
#define EC  32   // E-chunk staged in LDS
#define SRX 36   // LDS row stride for X tile (padded, 8B/16B aligned)
#define SRC 68   // LDS row stride for C tile (padded, 16B aligned)

// ---------------- K0: centroid squared norms in fp64 ----------------
__global__ __launch_bounds__(256) void k_csq(const float* __restrict__ cent,
                                             double* __restrict__ csq) {
  const int wave = blockIdx.x * 4 + (threadIdx.x >> 6);
  const int lane = threadIdx.x & 63;
  for (int r = 0; r < 16; ++r) {
    const int row = wave * 16 + r;               // 256 waves * 16 = 4096 rows
    const float* p = cent + (size_t)row * E_DIM;
    double s = 0.0;
#pragma unroll
    for (int i = 0; i < 16; ++i) {
      const float v = p[lane + i * 64];
      s += (double)v * (double)v;
    }
#pragma unroll
    for (int m = 32; m >= 1; m >>= 1) s += __shfl_xor(s, m, 64);
    if (lane == 0) csq[row] = s;
  }
}

// ---------------- K1: per-block model histogram (striped LDS) ----------------
__global__ __launch_bounds__(256) void k_hist(const int* __restrict__ midx,
                                              int* __restrict__ hist) {
  __shared__ int h[M_MODELS * 33];
  const int tid = threadIdx.x;
  for (int i = tid; i < M_MODELS * 33; i += 256) h[i] = 0;
  __syncthreads();
  const int base = blockIdx.x * 1024;
  const int st = tid & 31;
#pragma unroll
  for (int r = 0; r < 4; ++r) {
    const int m = midx[base + tid + r * 256];
    atomicAdd(&h[m * 33 + st], 1);
  }
  __syncthreads();
  if (tid < M_MODELS) {
    int s = 0;
    for (int j = 0; j < 32; ++j) s += h[tid * 33 + j];
    hist[blockIdx.x * M_MODELS + tid] = s;
  }
}

// ---------------- K2: scatter frames into per-model buckets ----------------
__global__ __launch_bounds__(256) void k_scatter(const int* __restrict__ midx,
                                                 const int* __restrict__ hist,
                                                 int* __restrict__ order,
                                                 int* __restrict__ offs) {
  __shared__ int h2[16 * M_MODELS];
  __shared__ int cur[M_MODELS];
  const int tid = threadIdx.x;
  if (tid < 16 * M_MODELS) h2[tid] = hist[tid];
  __syncthreads();
  if (tid < M_MODELS) {
    int tot_before = 0;
    for (int mp = 0; mp < tid; ++mp)
      for (int b = 0; b < 16; ++b) tot_before += h2[b * M_MODELS + mp];
    int prior = 0;
    for (int b = 0; b < (int)blockIdx.x; ++b) prior += h2[b * M_MODELS + tid];
    cur[tid] = tot_before + prior;
  }
  if (blockIdx.x == 0 && tid <= M_MODELS) {  // offs[0..8], offs[8]==T
    int o = 0;
    for (int mp = 0; mp < tid; ++mp)
      for (int b = 0; b < 16; ++b) o += h2[b * M_MODELS + mp];
    offs[tid] = o;
  }
  __syncthreads();
  const int base = blockIdx.x * 1024;
#pragma unroll
  for (int r = 0; r < 4; ++r) {
    const int f = base + tid + r * 256;
    const int m = midx[f];
    const int pos = atomicAdd(&cur[m], 1);
    order[pos] = f;
  }
}

// ---------------- K3: distances + argmin + gather (fused) ----------------
// Block: 256 threads as 16(tx) x 16(ty). Tile: FPB=32 frames x KC=64 centroids,
// thread tile 2 frames x 4 centroids. E staged in EC=32 chunks, transposed in
// LDS so compute reads are ds_read_b64/b128. fp32 chunk dot -> fp64 total.
__global__ __launch_bounds__(256) void k_dist(const float* __restrict__ emb,
                                              const float* __restrict__ cent,
                                              const double* __restrict__ csq,
                                              const int* __restrict__ order,
                                              const int* __restrict__ offs,
                                              float* __restrict__ out) {
  const int m = blockIdx.y;
  const int o0 = offs[m];
  const int cnt = offs[m + 1] - o0;
  const int start = blockIdx.x * FPB;
  if (start >= cnt) return;
  const int nvalid = min(FPB, cnt - start);

  __shared__ float Xs[EC * SRX];
  __shared__ float Cs[EC * SRC];
  __shared__ int rows_l[FPB];
  __shared__ int codes_l[FPB];

  const int tid = threadIdx.x;
  const int tx = tid & 15, ty = tid >> 4;

  if (tid < FPB) rows_l[tid] = order[o0 + start + min(tid, nvalid - 1)];
  __syncthreads();

  // staging assignment: one X float4 + two C float4 per thread
  const int s_row = tid >> 3;         // 0..31
  const int s_c4 = (tid & 7) * 4;     // e-offset within chunk: 0,4,...,28
  const size_t xrow_g = (size_t)rows_l[s_row] * E_DIM;
  const size_t cbase_a = ((size_t)m * K_CLUST + s_row) * E_DIM;        // +kc*KC rows
  const size_t cbase_b = ((size_t)m * K_CLUST + s_row + 32) * E_DIM;

  float4 gx = *(const float4*)(emb + xrow_g + s_c4);
  float4 ga = *(const float4*)(cent + cbase_a + s_c4);
  float4 gb = *(const float4*)(cent + cbase_b + s_c4);

  double bd0 = 1e300, bd1 = 1e300;
  int bi0 = 0, bi1 = 0;
  double a64[2][4] = {{0.0, 0.0, 0.0, 0.0}, {0.0, 0.0, 0.0, 0.0}};

  const int NIC = (K_CLUST / KC) * (E_DIM / EC);  // 8 * 32 = 256
  for (int ic = 0; ic < NIC; ++ic) {
    const int ec = ic & 31;
    // stage current chunk (regs -> LDS, transposed)
#pragma unroll
    for (int k = 0; k < 4; ++k) Xs[(s_c4 + k) * SRX + s_row] = (&gx.x)[k];
#pragma unroll
    for (int k = 0; k < 4; ++k) Cs[(s_c4 + k) * SRC + s_row] = (&ga.x)[k];
#pragma unroll
    for (int k = 0; k < 4; ++k) Cs[(s_c4 + k) * SRC + s_row + 32] = (&gb.x)[k];
    __syncthreads();

    // prefetch next chunk while computing
    if (ic + 1 < NIC) {
      const int kc2 = (ic + 1) >> 5;
      const int e02 = ((ic + 1) & 31) * EC;
      gx = *(const float4*)(emb + xrow_g + e02 + s_c4);
      ga = *(const float4*)(cent + cbase_a + (size_t)kc2 * KC * E_DIM + e02 + s_c4);
      gb = *(const float4*)(cent + cbase_b + (size_t)kc2 * KC * E_DIM + e02 + s_c4);
    }

    float acc[2][4] = {{0.f, 0.f, 0.f, 0.f}, {0.f, 0.f, 0.f, 0.f}};
#pragma unroll
    for (int e = 0; e < EC; ++e) {
      const float2 a = *(const float2*)(Xs + e * SRX + ty * 2);
      const float4 b = *(const float4*)(Cs + e * SRC + tx * 4);
      acc[0][0] += a.x * b.x; acc[0][1] += a.x * b.y;
      acc[0][2] += a.x * b.z; acc[0][3] += a.x * b.w;
      acc[1][0] += a.y * b.x; acc[1][1] += a.y * b.y;
      acc[1][2] += a.y * b.z; acc[1][3] += a.y * b.w;
    }
#pragma unroll
    for (int i = 0; i < 2; ++i)
#pragma unroll
      for (int j = 0; j < 4; ++j) a64[i][j] += (double)acc[i][j];
    __syncthreads();

    if (ec == 31) {  // finished full E for this centroid tile -> argmin update
      const int kc = ic >> 5;
#pragma unroll
      for (int j = 0; j < 4; ++j) {
        const int cidx = kc * KC + tx * 4 + j;
        const double cs = csq[m * K_CLUST + cidx];
        const double d0 = cs - 2.0 * a64[0][j];
        const double d1 = cs - 2.0 * a64[1][j];
        if (d0 < bd0) { bd0 = d0; bi0 = cidx; }
        if (d1 < bd1) { bd1 = d1; bi1 = cidx; }
        a64[0][j] = 0.0; a64[1][j] = 0.0;
      }
    }
  }

  // reduce across the 16 tx-lanes sharing each frame (first-index tie-break)
#pragma unroll
  for (int s = 8; s >= 1; s >>= 1) {
    const double od0 = __shfl_xor(bd0, s, 64);
    const int oi0 = __shfl_xor(bi0, s, 64);
    if (od0 < bd0 || (od0 == bd0 && oi0 < bi0)) { bd0 = od0; bi0 = oi0; }
    const double od1 = __shfl_xor(bd1, s, 64);
    const int oi1 = __shfl_xor(bi1, s, 64);
    if (od1 < bd1 || (od1 == bd1 && oi1 < bi1)) { bd1 = od1; bi1 = oi1; }
  }
  if (tx == 0) {
    codes_l[ty * 2 + 0] = bi0;
    codes_l[ty * 2 + 1] = bi1;
  }
  __syncthreads();

  // gather: copy winning centroid rows to out (1024 floats = 256 float4)
  for (int lf = 0; lf < nvalid; ++lf) {
    const int t = rows_l[lf];
    const int code = codes_l[lf];
    const float4* src = (const float4*)(cent + ((size_t)m * K_CLUST + code) * E_DIM);
    float4* dst = (float4*)(out + (size_t)t * E_DIM);
    dst[tid] = src[tid];
  }
}

extern "C" void kernel_launch(void* const* d_in, const int* in_sizes, int n_in,
                              void* d_out, int out_size, void* d_ws, size_t ws_size,
                              hipStream_t stream) {
  const float* emb = (const float*)d_in[0];     // [1,T,E] fp32
  const float* cent = (const float*)d_in[1];    // [M,K,E] fp32
  const int* midx = (const int*)d_in[2];        // [T] int32
  float* out = (float*)d_out;                   // [1,T,E] fp32

  char* ws = (char*)d_ws;                       // needs ~97 KB
  double* csq = (double*)(ws + 0);
  int* hist = (int*)(ws + 32768);
  int* offs = (int*)(ws + 33280);
  int* order = (int*)(ws + 33344);

  hipLaunchKernelGGL(k_csq, dim3(64), dim3(256), 0, stream, cent, csq);
  hipLaunchKernelGGL(k_hist, dim3(16), dim3(256), 0, stream, midx, hist);
  hipLaunchKernelGGL(k_scatter, dim3(16), dim3(256), 0, stream, midx, hist, order, offs);
  hipLaunchKernelGGL(k_dist, dim3(T_FRAMES / FPB, M_MODELS), dim3(256), 0, stream,
                     emb, cent, csq, order, offs, out);
}

// Round 2
// 288.336 us; speedup vs baseline: 2.5097x; 2.5097x over previous
//
#include <hip/hip_runtime.h>

// MultipleKmeans: T=16384 frames, E=1024, M=8 models, K=512 clusters.
// Round 2: bf16 MFMA (hi.hi single pass) for approx scores -> candidate
// window eps=3.0 -> exact fp64 recheck of candidates -> gather.
// Approx scores s[T,512] are staged in d_out cols [0,512) and overwritten
// by the gather, so ws stays ~113 KB.
//
// ws layout:
//   [     0, 32768): double csq64[M*K]
//   [ 32768, 49152): float  csq32[M*K]
//   [ 49152, 49664): int    hist[16][8]
//   [ 49664, 49728): int    offs[9]
//   [ 49728,115264): int    order[T]

#define T_FRAMES 16384
#define E_DIM    1024
#define M_MODELS 8
#define K_CLUST  512

#define FPB  64    // frames per block (k_dist)
#define CPB  256   // centroids per block (k_dist)
#define BK   32    // E-chunk per iteration
#define SA   40    // LDS row stride in bf16 elems (80 B: 16B-aligned, even bank spread)

typedef __bf16 bf16x8 __attribute__((ext_vector_type(8)));
typedef float  floatx16 __attribute__((ext_vector_type(16)));

// ---------------- K0: centroid squared norms (fp64 + fp32) ----------------
__global__ __launch_bounds__(256) void k_csq(const float* __restrict__ cent,
                                             double* __restrict__ csq64,
                                             float* __restrict__ csq32) {
  const int wave = blockIdx.x * 4 + (threadIdx.x >> 6);
  const int lane = threadIdx.x & 63;
  for (int r = 0; r < 16; ++r) {
    const int row = wave * 16 + r;               // 256 waves * 16 = 4096 rows
    const float* p = cent + (size_t)row * E_DIM;
    double s = 0.0;
#pragma unroll
    for (int i = 0; i < 16; ++i) {
      const float v = p[lane + i * 64];
      s += (double)v * (double)v;
    }
#pragma unroll
    for (int m = 32; m >= 1; m >>= 1) s += __shfl_xor(s, m, 64);
    if (lane == 0) { csq64[row] = s; csq32[row] = (float)s; }
  }
}

// ---------------- K1: per-block model histogram ----------------
__global__ __launch_bounds__(256) void k_hist(const int* __restrict__ midx,
                                              int* __restrict__ hist) {
  __shared__ int h[M_MODELS * 33];
  const int tid = threadIdx.x;
  for (int i = tid; i < M_MODELS * 33; i += 256) h[i] = 0;
  __syncthreads();
  const int base = blockIdx.x * 1024;
  const int st = tid & 31;
#pragma unroll
  for (int r = 0; r < 4; ++r) {
    const int m = midx[base + tid + r * 256];
    atomicAdd(&h[m * 33 + st], 1);
  }
  __syncthreads();
  if (tid < M_MODELS) {
    int s = 0;
    for (int j = 0; j < 32; ++j) s += h[tid * 33 + j];
    hist[blockIdx.x * M_MODELS + tid] = s;
  }
}

// ---------------- K2: scatter frames into per-model buckets ----------------
__global__ __launch_bounds__(256) void k_scatter(const int* __restrict__ midx,
                                                 const int* __restrict__ hist,
                                                 int* __restrict__ order,
                                                 int* __restrict__ offs) {
  __shared__ int h2[16 * M_MODELS];
  __shared__ int cur[M_MODELS];
  const int tid = threadIdx.x;
  if (tid < 16 * M_MODELS) h2[tid] = hist[tid];
  __syncthreads();
  if (tid < M_MODELS) {
    int tot_before = 0;
    for (int mp = 0; mp < tid; ++mp)
      for (int b = 0; b < 16; ++b) tot_before += h2[b * M_MODELS + mp];
    int prior = 0;
    for (int b = 0; b < (int)blockIdx.x; ++b) prior += h2[b * M_MODELS + tid];
    cur[tid] = tot_before + prior;
  }
  if (blockIdx.x == 0 && tid <= M_MODELS) {
    int o = 0;
    for (int mp = 0; mp < tid; ++mp)
      for (int b = 0; b < 16; ++b) o += h2[b * M_MODELS + mp];
    offs[tid] = o;
  }
  __syncthreads();
  const int base = blockIdx.x * 1024;
#pragma unroll
  for (int r = 0; r < 4; ++r) {
    const int f = base + tid + r * 256;
    const int m = midx[f];
    const int pos = atomicAdd(&cur[m], 1);
    order[pos] = f;
  }
}

__device__ inline bf16x8 cvt8(const float4 a, const float4 b) {
  bf16x8 h;
  h[0] = (__bf16)a.x; h[1] = (__bf16)a.y; h[2] = (__bf16)a.z; h[3] = (__bf16)a.w;
  h[4] = (__bf16)b.x; h[5] = (__bf16)b.y; h[6] = (__bf16)b.z; h[7] = (__bf16)b.w;
  return h;
}

// ---------------- K3: MFMA approx scores s = csq32 - 2*dot(hi,hi) ----------
// Block: 256 thr = 4 waves. Tile: 64 frames x 256 centroids; wave = 64x64
// (2x2 MFMA tiles of 32x32x16_bf16). grid = (T/FPB, M*2); y -> (model, half).
__global__ __launch_bounds__(256) void k_dist(const float* __restrict__ emb,
                                              const float* __restrict__ cent,
                                              const float* __restrict__ csq32,
                                              const int* __restrict__ order,
                                              const int* __restrict__ offs,
                                              float* __restrict__ out) {
  const int m = blockIdx.y >> 1;
  const int halfc = blockIdx.y & 1;           // centroid half: cols halfc*256 ..
  const int o0 = offs[m];
  const int cnt = offs[m + 1] - o0;
  const int start = blockIdx.x * FPB;
  if (start >= cnt) return;
  const int nvalid = min(FPB, cnt - start);

  __shared__ __align__(16) __bf16 A_l[FPB * SA];
  __shared__ __align__(16) __bf16 B_l[CPB * SA];
  __shared__ int rows_l[FPB];

  const int tid = threadIdx.x;
  if (tid < FPB) rows_l[tid] = order[o0 + start + min(tid, nvalid - 1)];
  __syncthreads();

  // staging roles
  const int rA = tid >> 2;            // 0..63  (frame row)
  const int gA = tid & 3;             // granule of 8 floats
  const size_t xbase4 = (size_t)rows_l[rA] * (E_DIM / 4) + gA * 2;
  const int growB = m * K_CLUST + halfc * CPB + tid;      // 0..255 local row
  const size_t cbase4 = (size_t)growB * (E_DIM / 4);

  const float4* emb4 = (const float4*)emb;
  const float4* cent4 = (const float4*)cent;

  float4 pa0 = emb4[xbase4], pa1 = emb4[xbase4 + 1];
  float4 pb[8];
#pragma unroll
  for (int i = 0; i < 8; ++i) pb[i] = cent4[cbase4 + i];

  floatx16 acc[4] = {};   // [a*2+b]: a = frame tile (0,1), b = col tile (0,1)

  const int l = tid & 63;
  const int w = tid >> 6;           // wave id -> col strip w*64
  const int ln = l & 31;
  const int lh = l >> 5;            // k-half within frag

  const int NIT = E_DIM / BK;       // 32
  for (int it = 0; it < NIT; ++it) {
    // regs -> LDS (fp32 -> bf16)
    *(bf16x8*)(A_l + rA * SA + gA * 8) = cvt8(pa0, pa1);
#pragma unroll
    for (int i = 0; i < 4; ++i)
      *(bf16x8*)(B_l + tid * SA + i * 8) = cvt8(pb[2 * i], pb[2 * i + 1]);
    __syncthreads();

    if (it + 1 < NIT) {
      pa0 = emb4[xbase4 + (it + 1) * 8];
      pa1 = emb4[xbase4 + (it + 1) * 8 + 1];
#pragma unroll
      for (int i = 0; i < 8; ++i) pb[i] = cent4[cbase4 + (it + 1) * 8 + i];
    }

#pragma unroll
    for (int s = 0; s < 2; ++s) {
      const int kb = s * 16 + lh * 8;
      const bf16x8 a0 = *(const bf16x8*)(A_l + ln * SA + kb);
      const bf16x8 a1 = *(const bf16x8*)(A_l + (32 + ln) * SA + kb);
      const bf16x8 b0 = *(const bf16x8*)(B_l + (w * 64 + ln) * SA + kb);
      const bf16x8 b1 = *(const bf16x8*)(B_l + (w * 64 + 32 + ln) * SA + kb);
      acc[0] = __builtin_amdgcn_mfma_f32_32x32x16_bf16(a0, b0, acc[0], 0, 0, 0);
      acc[1] = __builtin_amdgcn_mfma_f32_32x32x16_bf16(a0, b1, acc[1], 0, 0, 0);
      acc[2] = __builtin_amdgcn_mfma_f32_32x32x16_bf16(a1, b0, acc[2], 0, 0, 0);
      acc[3] = __builtin_amdgcn_mfma_f32_32x32x16_bf16(a1, b1, acc[3], 0, 0, 0);
    }
    __syncthreads();
  }

  // epilogue: s = csq - 2*dot -> out[t*1024 + col]  (cols 0..511 used as scratch)
  const int colg0 = halfc * CPB + w * 64 + ln;
  const int colg1 = colg0 + 32;
  const float cs0 = csq32[m * K_CLUST + colg0];
  const float cs1 = csq32[m * K_CLUST + colg1];
#pragma unroll
  for (int a = 0; a < 2; ++a) {
#pragma unroll
    for (int r = 0; r < 16; ++r) {
      const int frow = a * 32 + (r & 3) + 8 * (r >> 2) + 4 * lh;
      const int t = rows_l[frow];
      float* orow = out + (size_t)t * E_DIM;
      orow[colg0] = cs0 - 2.0f * acc[a * 2 + 0][r];
      orow[colg1] = cs1 - 2.0f * acc[a * 2 + 1][r];
    }
  }
}

// ---------------- K4: candidate window + exact fp64 recheck + gather -------
// 4 waves/block, one wave per frame.
__global__ __launch_bounds__(256) void k_pick(const float* __restrict__ emb,
                                              const float* __restrict__ cent,
                                              const double* __restrict__ csq64,
                                              const int* __restrict__ midx,
                                              float* __restrict__ out) {
  const int t = blockIdx.x * 4 + (threadIdx.x >> 6);
  const int l = threadIdx.x & 63;
  const int m = midx[t];

  const float4* orow4 = (const float4*)(out + (size_t)t * E_DIM);
  const float4 v0 = orow4[l * 2];
  const float4 v1 = orow4[l * 2 + 1];
  float sv[8] = {v0.x, v0.y, v0.z, v0.w, v1.x, v1.y, v1.z, v1.w};

  // wave argmin with first-index tie-break
  float bm = sv[0];
  int bc = l * 8;
#pragma unroll
  for (int j = 1; j < 8; ++j)
    if (sv[j] < bm) { bm = sv[j]; bc = l * 8 + j; }
#pragma unroll
  for (int s = 32; s >= 1; s >>= 1) {
    const float om = __shfl_xor(bm, s, 64);
    const int oc = __shfl_xor(bc, s, 64);
    if (om < bm || (om == bm && oc < bc)) { bm = om; bc = oc; }
  }

  const float thr = bm + 3.0f;
  unsigned long long bal[8];
  int ncand = 0;
#pragma unroll
  for (int j = 0; j < 8; ++j) {
    bal[j] = __ballot(sv[j] < thr);
    ncand += __popcll(bal[j]);
  }

  int best = bc;
  if (ncand > 1) {
    float4 xv[4];
#pragma unroll
    for (int q = 0; q < 4; ++q)
      xv[q] = *(const float4*)(emb + (size_t)t * E_DIM + q * 256 + l * 4);
    double bd = 1e300;
    int bi = 1 << 30;
#pragma unroll
    for (int j = 0; j < 8; ++j) {
      unsigned long long mb = bal[j];
      while (mb) {
        const int L = __ffsll(mb) - 1;
        mb &= mb - 1;
        const int c = L * 8 + j;
        const float* crow = cent + ((size_t)m * K_CLUST + c) * E_DIM;
        double s = 0.0;
#pragma unroll
        for (int q = 0; q < 4; ++q) {
          const float4 cv = *(const float4*)(crow + q * 256 + l * 4);
          s += (double)xv[q].x * (double)cv.x + (double)xv[q].y * (double)cv.y +
               (double)xv[q].z * (double)cv.z + (double)xv[q].w * (double)cv.w;
        }
#pragma unroll
        for (int sh = 32; sh >= 1; sh >>= 1) s += __shfl_xor(s, sh, 64);
        const double d = csq64[m * K_CLUST + c] - 2.0 * s;
        if (d < bd || (d == bd && c < bi)) { bd = d; bi = c; }
      }
    }
    best = bi;
  }

  // gather winning centroid row -> out
  const float* crow = cent + ((size_t)m * K_CLUST + best) * E_DIM;
  float* drow = out + (size_t)t * E_DIM;
#pragma unroll
  for (int q = 0; q < 4; ++q)
    *(float4*)(drow + q * 256 + l * 4) = *(const float4*)(crow + q * 256 + l * 4);
}

extern "C" void kernel_launch(void* const* d_in, const int* in_sizes, int n_in,
                              void* d_out, int out_size, void* d_ws, size_t ws_size,
                              hipStream_t stream) {
  const float* emb = (const float*)d_in[0];     // [1,T,E] fp32
  const float* cent = (const float*)d_in[1];    // [M,K,E] fp32
  const int* midx = (const int*)d_in[2];        // [T] int32
  float* out = (float*)d_out;                   // [1,T,E] fp32

  char* ws = (char*)d_ws;                       // ~113 KB
  double* csq64 = (double*)(ws + 0);
  float* csq32 = (float*)(ws + 32768);
  int* hist = (int*)(ws + 49152);
  int* offs = (int*)(ws + 49664);
  int* order = (int*)(ws + 49728);

  hipLaunchKernelGGL(k_csq, dim3(64), dim3(256), 0, stream, cent, csq64, csq32);
  hipLaunchKernelGGL(k_hist, dim3(16), dim3(256), 0, stream, midx, hist);
  hipLaunchKernelGGL(k_scatter, dim3(16), dim3(256), 0, stream, midx, hist, order, offs);
  hipLaunchKernelGGL(k_dist, dim3(T_FRAMES / FPB, M_MODELS * 2), dim3(256), 0, stream,
                     emb, cent, csq32, order, offs, out);
  hipLaunchKernelGGL(k_pick, dim3(T_FRAMES / 4), dim3(256), 0, stream,
                     emb, cent, csq64, midx, out);
}

// Round 3
// 208.630 us; speedup vs baseline: 3.4685x; 1.3820x over previous
//
#include <hip/hip_runtime.h>

// MultipleKmeans: T=16384 frames, E=1024, M=8 models, K=512 clusters.
// Round 3: bf16-preconverted swizzled B (parked in d_out's unused half),
// k_dist = 64 frames x 512 cols per block, A LDS-double-buffered,
// B direct global->register depth-2 prefetch, XCD-aware grid (m = x % 8).
//
// d_out region usage (64 MB):
//   rows 0..16383, cols [0,512)   : approx scores (k_dist out, k_pick in)
//   rows 0..4095,  cols [512,1024): swizzled bf16 centroids (k_cvt out, k_dist in)
//   k_pick overwrites every full row at the end (stream-ordered).
//
// ws layout (<= 100416 B, well under round-2's proven 115264):
//   [     0, 32768): double csq64[M*K]
//   [ 32768, 34816): int    hist[64][8]
//   [ 34816, 34880): int    offs[9]
//   [ 34880,100416): int    order[T]

#define T_FRAMES 16384
#define E_DIM    1024
#define M_MODELS 8
#define K_CLUST  512

#define FPB  64    // frames per k_dist block
#define NCH  8     // K chunks
#define CHG  16    // granules (8 k each) per chunk -> 128 k per chunk

typedef __bf16 bf16x8 __attribute__((ext_vector_type(8)));
typedef float  floatx16 __attribute__((ext_vector_type(16)));

__device__ __forceinline__ bf16x8 cvt8(const float4 a, const float4 b) {
  bf16x8 h;
  h[0] = (__bf16)a.x; h[1] = (__bf16)a.y; h[2] = (__bf16)a.z; h[3] = (__bf16)a.w;
  h[4] = (__bf16)b.x; h[5] = (__bf16)b.y; h[6] = (__bf16)b.z; h[7] = (__bf16)b.w;
  return h;
}

// ---------------- K0: centroid squared norms, one wave per row -------------
__global__ __launch_bounds__(256) void k_csq(const float* __restrict__ cent,
                                             double* __restrict__ csq64) {
  const int row = blockIdx.x * 4 + (threadIdx.x >> 6);   // 1024 blocks -> 4096 rows
  const int lane = threadIdx.x & 63;
  const float* p = cent + (size_t)row * E_DIM;
  double s = 0.0;
#pragma unroll
  for (int i = 0; i < 16; ++i) {
    const float v = p[lane + i * 64];
    s += (double)v * (double)v;
  }
#pragma unroll
  for (int m = 32; m >= 1; m >>= 1) s += __shfl_xor(s, m, 64);
  if (lane == 0) csq64[row] = s;
}

// ---------------- K0b: cent fp32 -> swizzled bf16 in d_out high halves -----
// Swizzle: granule G = ((m*16+cg)*128 + gk)*32 + ci   (cg=colgroup/32, ci=col&31,
// gk = k/8). Stored at float offset (G>>7)*1024 + 512 + (G&127)*4  (i.e. the
// [512,1024) half of row G>>7; rows 0..4095). 16B granules, 1KB-chunk aligned.
__global__ __launch_bounds__(256) void k_cvt(const float* __restrict__ cent,
                                             float* __restrict__ out) {
  const int b = blockIdx.x;              // 512 blocks
  const int m = b >> 6;
  const int cg = (b >> 2) & 15;
  const int q = b & 3;
  const int tid = threadIdx.x;
  const int ci = tid & 31;
  const int gk0 = q * 32 + (tid >> 5) * 4;
  const int B32 = (m * 16 + cg) * 32;
  const float* src = cent + ((size_t)(m * K_CLUST + cg * 32 + ci)) * E_DIM;
#pragma unroll
  for (int j = 0; j < 4; ++j) {
    const int gk = gk0 + j;
    const float4 a = *(const float4*)(src + gk * 8);
    const float4 bb = *(const float4*)(src + gk * 8 + 4);
    const size_t foff = (size_t)(B32 + (gk >> 2)) * 1024 + 512 +
                        ((gk & 3) * 32 + ci) * 4;
    *(bf16x8*)(out + foff) = cvt8(a, bb);
  }
}

// ---------------- K1: per-block model histogram (64 blocks x 256) ----------
__global__ __launch_bounds__(256) void k_hist(const int* __restrict__ midx,
                                              int* __restrict__ hist) {
  __shared__ int h[M_MODELS * 33];
  const int tid = threadIdx.x;
  for (int i = tid; i < M_MODELS * 33; i += 256) h[i] = 0;
  __syncthreads();
  const int m = midx[blockIdx.x * 256 + tid];
  atomicAdd(&h[m * 33 + (tid & 31)], 1);
  __syncthreads();
  if (tid < M_MODELS) {
    int s = 0;
    for (int j = 0; j < 32; ++j) s += h[tid * 33 + j];
    hist[blockIdx.x * M_MODELS + tid] = s;
  }
}

// ---------------- K2: scatter frames into per-model buckets ----------------
__global__ __launch_bounds__(256) void k_scatter(const int* __restrict__ midx,
                                                 const int* __restrict__ hist,
                                                 int* __restrict__ order,
                                                 int* __restrict__ offs) {
  __shared__ int h2[64 * M_MODELS];
  __shared__ int cur[M_MODELS];
  const int tid = threadIdx.x;
  h2[tid] = hist[tid];
  h2[tid + 256] = hist[tid + 256];
  __syncthreads();
  if (tid < M_MODELS) {
    int tot_before = 0;
    for (int mp = 0; mp < tid; ++mp)
      for (int b = 0; b < 64; ++b) tot_before += h2[b * M_MODELS + mp];
    int prior = 0;
    for (int b = 0; b < (int)blockIdx.x; ++b) prior += h2[b * M_MODELS + tid];
    cur[tid] = tot_before + prior;
  }
  if (blockIdx.x == 0 && tid <= M_MODELS) {
    int o = 0;
    for (int mp = 0; mp < tid; ++mp)
      for (int b = 0; b < 64; ++b) o += h2[b * M_MODELS + mp];
    offs[tid] = o;
  }
  __syncthreads();
  const int f = blockIdx.x * 256 + tid;
  const int pos = atomicAdd(&cur[midx[f]], 1);
  order[pos] = f;
}

// ---------------- K3: MFMA approx scores, 64 frames x 512 cols per block ---
// 256 thr = 4 waves; wave w -> col strip w*128 (4 col-tiles of 32).
// acc: 2 row-tiles x 4 col-tiles of 32x32 = 8 x floatx16.
// A: LDS granule-major [gl][row], 2 x 16KB double-buffered (chunk = 128 k).
// B: swizzled bf16 from d_out, direct-to-register, depth-2 ring prefetch.
// grid = (M, 40): linear block id % 8 == m -> per-model XCD L2 residency.
__global__ __launch_bounds__(256, 1) void k_dist(const float* __restrict__ emb,
                                                 const double* __restrict__ csq64,
                                                 const int* __restrict__ order,
                                                 const int* __restrict__ offs,
                                                 float* __restrict__ out) {
  const int m = blockIdx.x;
  const int o0 = offs[m];
  const int cnt = offs[m + 1] - o0;
  const int start = blockIdx.y * FPB;
  if (start >= cnt) return;
  const int nvalid = min(FPB, cnt - start);

  __shared__ __align__(16) __bf16 A_l[2 * CHG * FPB * 8];   // 32 KB

  const int tid = threadIdx.x;
  const int l = tid & 63;
  const int w = tid >> 6;
  const int ln = l & 31;
  const int lh = l >> 5;

  // ---- A staging role: thread owns frame row (tid>>2), granules s_g..s_g+3
  const int s_row = tid >> 2;
  const int s_g = (tid & 3) * 4;
  const size_t arow4 = (size_t)order[o0 + start + min(s_row, nvalid - 1)] * (E_DIM / 4);
  const float4* emb4 = (const float4*)emb;

  float4 pa[8];
#pragma unroll
  for (int j = 0; j < 4; ++j) {
    pa[2 * j] = emb4[arow4 + (s_g + j) * 2];
    pa[2 * j + 1] = emb4[arow4 + (s_g + j) * 2 + 1];
  }
#pragma unroll
  for (int j = 0; j < 4; ++j)
    *(bf16x8*)(A_l + ((size_t)(s_g + j) * FPB + s_row) * 8) = cvt8(pa[2 * j], pa[2 * j + 1]);

  // ---- B base pointers (swizzled bf16 region in d_out)
  const char* bbase[4];
#pragma unroll
  for (int ct = 0; ct < 4; ++ct) {
    const int cg = w * 4 + ct;
    bbase[ct] = (const char*)out + (size_t)(m * 16 + cg) * 131072 + 2048 + l * 16;
  }
#define LOADB(ct, kb) (*(const bf16x8*)(bbase[ct] + (((kb) >> 1) << 12) + (((kb) & 1) << 10)))

  bf16x8 bR[2][4];
#pragma unroll
  for (int ct = 0; ct < 4; ++ct) {
    bR[0][ct] = LOADB(ct, 0);
    bR[1][ct] = LOADB(ct, 1);
  }

  floatx16 acc[8] = {};
  __syncthreads();

  for (int c = 0; c < NCH; ++c) {
    const int buf = (c & 1) * CHG;
    // prefetch next A chunk into registers (in flight across this chunk's MFMAs)
    if (c + 1 < NCH) {
#pragma unroll
      for (int j = 0; j < 4; ++j) {
        pa[2 * j] = emb4[arow4 + (c + 1) * 32 + (s_g + j) * 2];
        pa[2 * j + 1] = emb4[arow4 + (c + 1) * 32 + (s_g + j) * 2 + 1];
      }
    }
#pragma unroll
    for (int jj = 0; jj < 8; ++jj) {
      const int kb = c * 8 + jj;
      const int p = jj & 1;
      const bf16x8 a0 = *(const bf16x8*)(A_l + ((size_t)(buf + jj * 2 + lh) * FPB + ln) * 8);
      const bf16x8 a1 = *(const bf16x8*)(A_l + ((size_t)(buf + jj * 2 + lh) * FPB + 32 + ln) * 8);
#pragma unroll
      for (int ct = 0; ct < 4; ++ct) {
        acc[ct] = __builtin_amdgcn_mfma_f32_32x32x16_bf16(a0, bR[p][ct], acc[ct], 0, 0, 0);
        acc[4 + ct] = __builtin_amdgcn_mfma_f32_32x32x16_bf16(a1, bR[p][ct], acc[4 + ct], 0, 0, 0);
      }
      if (kb + 2 < 64) {
#pragma unroll
        for (int ct = 0; ct < 4; ++ct) bR[p][ct] = LOADB(ct, kb + 2);
      }
    }
    __syncthreads();
    if (c + 1 < NCH) {
      const int nbuf = ((c + 1) & 1) * CHG;
#pragma unroll
      for (int j = 0; j < 4; ++j)
        *(bf16x8*)(A_l + ((size_t)(nbuf + s_g + j) * FPB + s_row) * 8) = cvt8(pa[2 * j], pa[2 * j + 1]);
      __syncthreads();
    }
  }

  // ---- epilogue: s = csq - 2*dot -> out[t*1024 + col], cols 0..511
#pragma unroll
  for (int ct = 0; ct < 4; ++ct) {
    const int col = w * 128 + ct * 32 + ln;
    const float cs = (float)csq64[m * K_CLUST + col];
#pragma unroll
    for (int rt = 0; rt < 2; ++rt) {
#pragma unroll
      for (int r = 0; r < 16; ++r) {
        const int frow = rt * 32 + (r & 3) + 8 * (r >> 2) + 4 * lh;
        const int t = order[o0 + start + min(frow, nvalid - 1)];
        out[(size_t)t * E_DIM + col] = cs - 2.0f * acc[rt * 4 + ct][r];
      }
    }
  }
#undef LOADB
}

// ---------------- K4: candidate window + exact fp64 recheck + gather -------
__global__ __launch_bounds__(256) void k_pick(const float* __restrict__ emb,
                                              const float* __restrict__ cent,
                                              const double* __restrict__ csq64,
                                              const int* __restrict__ midx,
                                              float* __restrict__ out) {
  const int t = blockIdx.x * 4 + (threadIdx.x >> 6);
  const int l = threadIdx.x & 63;
  const int m = midx[t];

  const float4* orow4 = (const float4*)(out + (size_t)t * E_DIM);
  const float4 v0 = orow4[l * 2];
  const float4 v1 = orow4[l * 2 + 1];
  float sv[8] = {v0.x, v0.y, v0.z, v0.w, v1.x, v1.y, v1.z, v1.w};

  float bm = sv[0];
  int bc = l * 8;
#pragma unroll
  for (int j = 1; j < 8; ++j)
    if (sv[j] < bm) { bm = sv[j]; bc = l * 8 + j; }
#pragma unroll
  for (int s = 32; s >= 1; s >>= 1) {
    const float om = __shfl_xor(bm, s, 64);
    const int oc = __shfl_xor(bc, s, 64);
    if (om < bm || (om == bm && oc < bc)) { bm = om; bc = oc; }
  }

  const float thr = bm + 3.0f;
  unsigned long long bal[8];
  int ncand = 0;
#pragma unroll
  for (int j = 0; j < 8; ++j) {
    bal[j] = __ballot(sv[j] < thr);
    ncand += __popcll(bal[j]);
  }

  int best = bc;
  if (ncand > 1) {
    float4 xv[4];
#pragma unroll
    for (int q = 0; q < 4; ++q)
      xv[q] = *(const float4*)(emb + (size_t)t * E_DIM + q * 256 + l * 4);
    double bd = 1e300;
    int bi = 1 << 30;
#pragma unroll
    for (int j = 0; j < 8; ++j) {
      unsigned long long mb = bal[j];
      while (mb) {
        const int L = __ffsll(mb) - 1;
        mb &= mb - 1;
        const int c = L * 8 + j;
        const float* crow = cent + ((size_t)m * K_CLUST + c) * E_DIM;
        double s = 0.0;
#pragma unroll
        for (int q = 0; q < 4; ++q) {
          const float4 cv = *(const float4*)(crow + q * 256 + l * 4);
          s += (double)xv[q].x * (double)cv.x + (double)xv[q].y * (double)cv.y +
               (double)xv[q].z * (double)cv.z + (double)xv[q].w * (double)cv.w;
        }
#pragma unroll
        for (int sh = 32; sh >= 1; sh >>= 1) s += __shfl_xor(s, sh, 64);
        const double d = csq64[m * K_CLUST + c] - 2.0 * s;
        if (d < bd || (d == bd && c < bi)) { bd = d; bi = c; }
      }
    }
    best = bi;
  }

  const float* crow = cent + ((size_t)m * K_CLUST + best) * E_DIM;
  float* drow = out + (size_t)t * E_DIM;
#pragma unroll
  for (int q = 0; q < 4; ++q)
    *(float4*)(drow + q * 256 + l * 4) = *(const float4*)(crow + q * 256 + l * 4);
}

extern "C" void kernel_launch(void* const* d_in, const int* in_sizes, int n_in,
                              void* d_out, int out_size, void* d_ws, size_t ws_size,
                              hipStream_t stream) {
  const float* emb = (const float*)d_in[0];     // [1,T,E] fp32
  const float* cent = (const float*)d_in[1];    // [M,K,E] fp32
  const int* midx = (const int*)d_in[2];        // [T] int32
  float* out = (float*)d_out;                   // [1,T,E] fp32

  char* ws = (char*)d_ws;                       // ~100 KB
  double* csq64 = (double*)(ws + 0);
  int* hist = (int*)(ws + 32768);
  int* offs = (int*)(ws + 34816);
  int* order = (int*)(ws + 34880);

  hipLaunchKernelGGL(k_csq, dim3(1024), dim3(256), 0, stream, cent, csq64);
  hipLaunchKernelGGL(k_cvt, dim3(512), dim3(256), 0, stream, cent, out);
  hipLaunchKernelGGL(k_hist, dim3(64), dim3(256), 0, stream, midx, hist);
  hipLaunchKernelGGL(k_scatter, dim3(64), dim3(256), 0, stream, midx, hist, order, offs);
  hipLaunchKernelGGL(k_dist, dim3(M_MODELS, 40), dim3(256), 0, stream,
                     emb, csq64, order, offs, out);
  hipLaunchKernelGGL(k_pick, dim3(T_FRAMES / 4), dim3(256), 0, stream,
                     emb, cent, csq64, midx, out);
}

// Round 4
// 205.935 us; speedup vs baseline: 3.5139x; 1.0131x over previous
//
#include <hip/hip_runtime.h>

// MultipleKmeans: T=16384 frames, E=1024, M=8 models, K=512 clusters.
// Round 4: fully fused k_dist (MFMA scores in regs -> block argmin ->
// eps=3.0 candidate window -> in-block exact fp64 recheck -> code word),
// FPB=32 for 2 blocks/CU, depth-4 B prefetch ring, 1 barrier/chunk.
// Codes parked at out[t*1024] (col 0; B lives in cols[512,1024) of rows
// 0..4095 -> no overlap). k_gather expands codes -> output rows.
//
// ws layout (same as round 3, <=100416 B):
//   [     0, 32768): double csq64[M*K]
//   [ 32768, 34816): int    hist[64][8]
//   [ 34816, 34880): int    offs[9]
//   [ 34880,100416): int    order[T]

#define T_FRAMES 16384
#define E_DIM    1024
#define M_MODELS 8
#define K_CLUST  512

#define FPB 32     // frames per k_dist block
#define NCH 8      // K chunks of 128

typedef __bf16 bf16x8 __attribute__((ext_vector_type(8)));
typedef float  floatx16 __attribute__((ext_vector_type(16)));

__device__ __forceinline__ bf16x8 cvt8(const float4 a, const float4 b) {
  bf16x8 h;
  h[0] = (__bf16)a.x; h[1] = (__bf16)a.y; h[2] = (__bf16)a.z; h[3] = (__bf16)a.w;
  h[4] = (__bf16)b.x; h[5] = (__bf16)b.y; h[6] = (__bf16)b.z; h[7] = (__bf16)b.w;
  return h;
}

// ---------------- K0: centroid squared norms, one wave per row -------------
__global__ __launch_bounds__(256) void k_csq(const float* __restrict__ cent,
                                             double* __restrict__ csq64) {
  const int row = blockIdx.x * 4 + (threadIdx.x >> 6);
  const int lane = threadIdx.x & 63;
  const float* p = cent + (size_t)row * E_DIM;
  double s = 0.0;
#pragma unroll
  for (int i = 0; i < 16; ++i) {
    const float v = p[lane + i * 64];
    s += (double)v * (double)v;
  }
#pragma unroll
  for (int m = 32; m >= 1; m >>= 1) s += __shfl_xor(s, m, 64);
  if (lane == 0) csq64[row] = s;
}

// ---------------- K0b: cent fp32 -> swizzled bf16 in d_out high halves -----
__global__ __launch_bounds__(256) void k_cvt(const float* __restrict__ cent,
                                             float* __restrict__ out) {
  const int b = blockIdx.x;              // 512 blocks
  const int m = b >> 6;
  const int cg = (b >> 2) & 15;
  const int q = b & 3;
  const int tid = threadIdx.x;
  const int ci = tid & 31;
  const int gk0 = q * 32 + (tid >> 5) * 4;
  const int B32 = (m * 16 + cg) * 32;
  const float* src = cent + ((size_t)(m * K_CLUST + cg * 32 + ci)) * E_DIM;
#pragma unroll
  for (int j = 0; j < 4; ++j) {
    const int gk = gk0 + j;
    const float4 a = *(const float4*)(src + gk * 8);
    const float4 bb = *(const float4*)(src + gk * 8 + 4);
    const size_t foff = (size_t)(B32 + (gk >> 2)) * 1024 + 512 +
                        ((gk & 3) * 32 + ci) * 4;
    *(bf16x8*)(out + foff) = cvt8(a, bb);
  }
}

// ---------------- K1: per-block model histogram ----------------------------
__global__ __launch_bounds__(256) void k_hist(const int* __restrict__ midx,
                                              int* __restrict__ hist) {
  __shared__ int h[M_MODELS * 33];
  const int tid = threadIdx.x;
  for (int i = tid; i < M_MODELS * 33; i += 256) h[i] = 0;
  __syncthreads();
  const int m = midx[blockIdx.x * 256 + tid];
  atomicAdd(&h[m * 33 + (tid & 31)], 1);
  __syncthreads();
  if (tid < M_MODELS) {
    int s = 0;
    for (int j = 0; j < 32; ++j) s += h[tid * 33 + j];
    hist[blockIdx.x * M_MODELS + tid] = s;
  }
}

// ---------------- K2: scatter frames into per-model buckets ----------------
__global__ __launch_bounds__(256) void k_scatter(const int* __restrict__ midx,
                                                 const int* __restrict__ hist,
                                                 int* __restrict__ order,
                                                 int* __restrict__ offs) {
  __shared__ int h2[64 * M_MODELS];
  __shared__ int cur[M_MODELS];
  const int tid = threadIdx.x;
  h2[tid] = hist[tid];
  h2[tid + 256] = hist[tid + 256];
  __syncthreads();
  if (tid < M_MODELS) {
    int tot_before = 0;
    for (int mp = 0; mp < tid; ++mp)
      for (int b = 0; b < 64; ++b) tot_before += h2[b * M_MODELS + mp];
    int prior = 0;
    for (int b = 0; b < (int)blockIdx.x; ++b) prior += h2[b * M_MODELS + tid];
    cur[tid] = tot_before + prior;
  }
  if (blockIdx.x == 0 && tid <= M_MODELS) {
    int o = 0;
    for (int mp = 0; mp < tid; ++mp)
      for (int b = 0; b < 64; ++b) o += h2[b * M_MODELS + mp];
    offs[tid] = o;
  }
  __syncthreads();
  const int f = blockIdx.x * 256 + tid;
  const int pos = atomicAdd(&cur[midx[f]], 1);
  order[pos] = f;
}

// ---------------- K3: fused scores + argmin + recheck -> code word ---------
// Block: 4 waves, tile = 32 frames x 512 cols (wave w -> cols [w*128,w*128+128)).
// acc: 4 x 32x32 tiles = 64 regs. A: LDS chunks of 128 k, double-buffered
// (16 KB). B: swizzled bf16 (d_out rows 0..4095 high halves), depth-4 ring.
// grid = (M, 80): linear id % 8 == m -> per-model XCD L2 residency.
__global__ __launch_bounds__(256, 2) void k_dist(const float* __restrict__ emb,
                                                 const float* __restrict__ cent,
                                                 const double* __restrict__ csq64,
                                                 const int* __restrict__ order,
                                                 const int* __restrict__ offs,
                                                 float* __restrict__ out) {
  const int m = blockIdx.x;
  const int o0 = offs[m];
  const int cnt = offs[m + 1] - o0;
  const int start = blockIdx.y * FPB;
  if (start >= cnt) return;
  const int nvalid = min(FPB, cnt - start);

  __shared__ __align__(16) __bf16 A_l[2 * 16 * FPB * 8];  // 16 KB
  __shared__ int rows_l[FPB];
  __shared__ float wmin_s[4][FPB];
  __shared__ int wcol_s[4][FPB];
  __shared__ float gmin_s[FPB];
  __shared__ int cnt_s[FPB];
  __shared__ int cand_s[FPB][32];

  const int tid = threadIdx.x;
  const int l = tid & 63;
  const int w = tid >> 6;
  const int ln = l & 31;
  const int lh = l >> 5;

  if (tid < FPB) rows_l[tid] = order[o0 + start + min(tid, nvalid - 1)];
  __syncthreads();

  // A staging role: thread -> row (tid&31), k-granule pair (tid>>5)
  const int s_row = tid & 31;
  const int s_gp = tid >> 5;                     // 0..7
  const float4* emb4 = (const float4*)emb;
  const size_t arow4 = (size_t)rows_l[s_row] * (E_DIM / 4);

  float4 pa[4];
#pragma unroll
  for (int j = 0; j < 4; ++j) pa[j] = emb4[arow4 + s_gp * 4 + j];
  *(bf16x8*)(A_l + ((s_gp * 2 + 0) * FPB + s_row) * 8) = cvt8(pa[0], pa[1]);
  *(bf16x8*)(A_l + ((s_gp * 2 + 1) * FPB + s_row) * 8) = cvt8(pa[2], pa[3]);

  // B base pointers (swizzled bf16 region in d_out)
  const char* bbase[4];
#pragma unroll
  for (int ct = 0; ct < 4; ++ct) {
    const int cg = w * 4 + ct;
    bbase[ct] = (const char*)out + (size_t)(m * 16 + cg) * 131072 + 2048 + l * 16;
  }
#define LOADB(ct, kb) (*(const bf16x8*)(bbase[ct] + (((kb) >> 1) << 12) + (((kb) & 1) << 10)))

  bf16x8 bR[4][4];                               // depth-4 ring
#pragma unroll
  for (int d = 0; d < 4; ++d)
#pragma unroll
    for (int ct = 0; ct < 4; ++ct) bR[d][ct] = LOADB(ct, d);

  floatx16 acc[4] = {};

  for (int c = 0; c < NCH; ++c) {
    __syncthreads();                             // A buf (c&1) ready
    const int buf = (c & 1) * 16;
    if (c + 1 < NCH) {
#pragma unroll
      for (int j = 0; j < 4; ++j) pa[j] = emb4[arow4 + (c + 1) * 32 + s_gp * 4 + j];
    }
#pragma unroll
    for (int jj = 0; jj < 8; ++jj) {
      const int kb = c * 8 + jj;
      const int p = kb & 3;
      const bf16x8 a0 = *(const bf16x8*)(A_l + ((buf + jj * 2 + lh) * FPB + ln) * 8);
#pragma unroll
      for (int ct = 0; ct < 4; ++ct)
        acc[ct] = __builtin_amdgcn_mfma_f32_32x32x16_bf16(a0, bR[p][ct], acc[ct], 0, 0, 0);
      if (kb + 4 < 64) {
#pragma unroll
        for (int ct = 0; ct < 4; ++ct) bR[p][ct] = LOADB(ct, kb + 4);
      }
    }
    if (c + 1 < NCH) {                           // write other buffer
      const int nbuf = ((c + 1) & 1) * 16;
      *(bf16x8*)(A_l + ((nbuf + s_gp * 2 + 0) * FPB + s_row) * 8) = cvt8(pa[0], pa[1]);
      *(bf16x8*)(A_l + ((nbuf + s_gp * 2 + 1) * FPB + s_row) * 8) = cvt8(pa[2], pa[3]);
    }
  }
#undef LOADB

  // ---- per-wave argmin (scores s = csq - 2*dot stay in regs) ----
  float cs[4];
#pragma unroll
  for (int ct = 0; ct < 4; ++ct)
    cs[ct] = (float)csq64[m * K_CLUST + w * 128 + ct * 32 + ln];

#pragma unroll
  for (int r = 0; r < 16; ++r) {
    const int fr = (r & 3) + 8 * (r >> 2) + 4 * lh;
    float bm = cs[0] - 2.0f * acc[0][r];
    int bc = w * 128 + ln;
#pragma unroll
    for (int ct = 1; ct < 4; ++ct) {
      const float s = cs[ct] - 2.0f * acc[ct][r];
      if (s < bm) { bm = s; bc = w * 128 + ct * 32 + ln; }
    }
#pragma unroll
    for (int sh = 1; sh <= 16; sh <<= 1) {       // reduce within lane-half
      const float om = __shfl_xor(bm, sh, 64);
      const int oc = __shfl_xor(bc, sh, 64);
      if (om < bm || (om == bm && oc < bc)) { bm = om; bc = oc; }
    }
    if (ln == 0) { wmin_s[w][fr] = bm; wcol_s[w][fr] = bc; }
  }
  __syncthreads();

  if (tid < FPB) {                               // cross-wave min
    float g = wmin_s[0][tid];
    int gc = wcol_s[0][tid];
#pragma unroll
    for (int w2 = 1; w2 < 4; ++w2) {
      const float v = wmin_s[w2][tid];
      const int vc = wcol_s[w2][tid];
      if (v < g || (v == g && vc < gc)) { g = v; gc = vc; }
    }
    gmin_s[tid] = g;
    cnt_s[tid] = 0;
  }
  __syncthreads();

  // ---- candidate collection within eps = 3.0 ----
#pragma unroll
  for (int r = 0; r < 16; ++r) {
    const int fr = (r & 3) + 8 * (r >> 2) + 4 * lh;
    const float thr = gmin_s[fr] + 3.0f;
#pragma unroll
    for (int ct = 0; ct < 4; ++ct) {
      const float s = cs[ct] - 2.0f * acc[ct][r];
      if (s < thr) {
        const int ix = atomicAdd(&cnt_s[fr], 1);
        if (ix < 32) cand_s[fr][ix] = w * 128 + ct * 32 + ln;
      }
    }
  }
  __syncthreads();

  // ---- resolution: wave w -> frames w*8 .. w*8+7; exact fp64 recheck ----
  for (int i = 0; i < 8; ++i) {
    const int f = w * 8 + i;
    const int t = rows_l[f];
    const int n = min(cnt_s[f], 32);
    int code;
    if (n == 1) {
      code = cand_s[f][0];
    } else {
      float4 xv[4];
#pragma unroll
      for (int q = 0; q < 4; ++q) xv[q] = emb4[(size_t)t * (E_DIM / 4) + q * 64 + l];
      double bd = 1e300;
      int bi = 1 << 30;
      for (int j = 0; j < n; ++j) {
        const int cc = cand_s[f][j];
        const float4* crow4 = (const float4*)(cent + ((size_t)(m * K_CLUST + cc)) * E_DIM);
        double s = 0.0;
#pragma unroll
        for (int q = 0; q < 4; ++q) {
          const float4 cv = crow4[q * 64 + l];
          s += (double)xv[q].x * cv.x + (double)xv[q].y * cv.y +
               (double)xv[q].z * cv.z + (double)xv[q].w * cv.w;
        }
#pragma unroll
        for (int sh = 32; sh >= 1; sh >>= 1) s += __shfl_xor(s, sh, 64);
        const double d = csq64[m * K_CLUST + cc] - 2.0 * s;
        if (d < bd || (d == bd && cc < bi)) { bd = d; bi = cc; }
      }
      code = bi;
    }
    if (l == 0) *(int*)(out + (size_t)t * E_DIM) = code;   // col 0: no B overlap
  }
}

// ---------------- K4: expand codes -> output rows --------------------------
__global__ __launch_bounds__(256) void k_gather(const float* __restrict__ cent,
                                                const int* __restrict__ midx,
                                                float* __restrict__ out) {
  const int t = blockIdx.x * 4 + (threadIdx.x >> 6);
  const int l = threadIdx.x & 63;
  float* drow = out + (size_t)t * E_DIM;
  const int code = *(const int*)drow;            // read before overwrite (dep-ordered)
  const int m = midx[t];
  const float4* src = (const float4*)(cent + ((size_t)(m * K_CLUST + code)) * E_DIM);
  float4* dst = (float4*)drow;
#pragma unroll
  for (int q = 0; q < 4; ++q) dst[q * 64 + l] = src[q * 64 + l];
}

extern "C" void kernel_launch(void* const* d_in, const int* in_sizes, int n_in,
                              void* d_out, int out_size, void* d_ws, size_t ws_size,
                              hipStream_t stream) {
  const float* emb = (const float*)d_in[0];     // [1,T,E] fp32
  const float* cent = (const float*)d_in[1];    // [M,K,E] fp32
  const int* midx = (const int*)d_in[2];        // [T] int32
  float* out = (float*)d_out;                   // [1,T,E] fp32

  char* ws = (char*)d_ws;                       // ~100 KB
  double* csq64 = (double*)(ws + 0);
  int* hist = (int*)(ws + 32768);
  int* offs = (int*)(ws + 34816);
  int* order = (int*)(ws + 34880);

  hipLaunchKernelGGL(k_cvt, dim3(512), dim3(256), 0, stream, cent, out);
  hipLaunchKernelGGL(k_csq, dim3(1024), dim3(256), 0, stream, cent, csq64);
  hipLaunchKernelGGL(k_hist, dim3(64), dim3(256), 0, stream, midx, hist);
  hipLaunchKernelGGL(k_scatter, dim3(64), dim3(256), 0, stream, midx, hist, order, offs);
  hipLaunchKernelGGL(k_dist, dim3(M_MODELS, 80), dim3(256), 0, stream,
                     emb, cent, csq64, order, offs, out);
  hipLaunchKernelGGL(k_gather, dim3(T_FRAMES / 4), dim3(256), 0, stream,
                     cent, midx, out);
}